// Round 1
// baseline (2752.770 us; speedup 1.0000x reference)
//
#include <hip/hip_runtime.h>
#include <hip/hip_bf16.h>

#define TT 2048
#define BB 4
#define HH 4
#define DD 1024

__device__ __forceinline__ float wave_sum(float x) {
#pragma unroll
  for (int off = 32; off >= 1; off >>= 1) x += __shfl_xor(x, off);
  return x;
}

__device__ __forceinline__ float siluf(float x) {
  return x / (1.f + expf(-x));
}

// ---------------- fp32 tiled GEMM: C[M,N] = A[M,K] @ B[K,N], row-major ----
__global__ __launch_bounds__(256) void sgemm_nn(const float* __restrict__ A,
                                                const float* __restrict__ B,
                                                float* __restrict__ C, int M,
                                                int N, int K) {
  __shared__ float As[16][64];
  __shared__ float Bs[16][64];
  const int tid = threadIdx.x;
  const int brow = blockIdx.y * 64;
  const int bcol = blockIdx.x * 64;
  const int tm = (tid >> 4) << 2;   // 0..60
  const int tn = (tid & 15) << 2;   // 0..60
  const int la_r = tid >> 2;        // 0..63
  const int la_k = (tid & 3) << 2;  // 0,4,8,12
  const int lb_k = tid >> 4;        // 0..15
  const int lb_n = (tid & 15) << 2; // 0..60
  float acc[4][4];
#pragma unroll
  for (int i = 0; i < 4; ++i)
#pragma unroll
    for (int jj = 0; jj < 4; ++jj) acc[i][jj] = 0.f;

  for (int k0 = 0; k0 < K; k0 += 16) {
    float4 av = *(const float4*)(A + (size_t)(brow + la_r) * K + k0 + la_k);
    float4 bv = *(const float4*)(B + (size_t)(k0 + lb_k) * N + bcol + lb_n);
    __syncthreads();
    As[la_k + 0][la_r] = av.x;
    As[la_k + 1][la_r] = av.y;
    As[la_k + 2][la_r] = av.z;
    As[la_k + 3][la_r] = av.w;
    *(float4*)(&Bs[lb_k][lb_n]) = bv;
    __syncthreads();
#pragma unroll
    for (int kk = 0; kk < 16; ++kk) {
      float4 a4 = *(const float4*)(&As[kk][tm]);
      float4 b4 = *(const float4*)(&Bs[kk][tn]);
      float a_[4] = {a4.x, a4.y, a4.z, a4.w};
      float b_[4] = {b4.x, b4.y, b4.z, b4.w};
#pragma unroll
      for (int i = 0; i < 4; ++i)
#pragma unroll
        for (int jj = 0; jj < 4; ++jj) acc[i][jj] = fmaf(a_[i], b_[jj], acc[i][jj]);
    }
  }
#pragma unroll
  for (int i = 0; i < 4; ++i) {
    float4 r = make_float4(acc[i][0], acc[i][1], acc[i][2], acc[i][3]);
    *(float4*)(C + (size_t)(brow + tm + i) * N + bcol + tn) = r;
  }
}

// ---------------- routing: a/beta dots, top-4, silu+norms, dense decay ----
__global__ __launch_bounds__(256) void routing_kernel(
    const float* __restrict__ hidden, const float* __restrict__ Wa,
    const float* __restrict__ Wb, const float* __restrict__ dt,
    const float* __restrict__ rproj, float* __restrict__ qk,
    float* __restrict__ kk_, float* __restrict__ vv, float* __restrict__ decT,
    float* __restrict__ betaT) {
  const int row = blockIdx.x;  // b*T + t
  const int b = row >> 11;
  const int t = row & (TT - 1);
  const int h = threadIdx.x >> 6;
  const int l = threadIdx.x & 63;
  const size_t base = (size_t)row * DD + h * 256;

  // --- a, beta (fused tiny GEMMs) ---
  const float* hrow = hidden + (size_t)row * DD;
  float aa = 0.f, bb = 0.f;
#pragma unroll
  for (int i = 0; i < 16; ++i) {
    float hv = hrow[l + 64 * i];
    aa = fmaf(hv, Wa[(l + 64 * i) * HH + h], aa);
    bb = fmaf(hv, Wb[(l + 64 * i) * HH + h], bb);
  }
  aa = wave_sum(aa);
  bb = wave_sum(bb);
  float sp = (aa > 20.f) ? aa : log1pf(expf(aa));
  float a_ = -sp * expf(dt[h]);
  float beta = 1.f / (1.f + expf(-bb));
  const int bh = b * HH + h;
  if (l == 0) betaT[(size_t)bh * TT + t] = beta;

  // --- top-4 of rt (argmax on pre-sigmoid values; sigmoid monotonic) ---
  float4 rt4 = *(const float4*)(rproj + base + l * 4);
  float rv[4] = {rt4.x, rt4.y, rt4.z, rt4.w};
  int used = 0;
  int widx[4];
  float wsig[4], wdec[4], wkfac[4];
#pragma unroll
  for (int it = 0; it < 4; ++it) {
    float bv = -3.4e38f;
    int bi = 0x7fffffff;
#pragma unroll
    for (int c = 0; c < 4; ++c) {
      bool ok = !(used & (1 << c));
      float v = rv[c];
      if (ok && (v > bv)) {
        bv = v;
        bi = l * 4 + c;
      }
    }
#pragma unroll
    for (int off = 32; off >= 1; off >>= 1) {
      float ov = __shfl_xor(bv, off);
      int oi = __shfl_xor(bi, off);
      if (ov > bv || (ov == bv && oi < bi)) {
        bv = ov;
        bi = oi;
      }
    }
    widx[it] = bi;
    wsig[it] = 1.f / (1.f + expf(-bv));
    if ((bi >> 2) == l) used |= 1 << (bi & 3);
  }
  float wsum = wsig[0] + wsig[1] + wsig[2] + wsig[3] + 1e-6f;
#pragma unroll
  for (int it = 0; it < 4; ++it) {
    float g = a_ * (wsig[it] / wsum);
    wdec[it] = expf(g);
    wkfac[it] = 1.f - wdec[it];
  }

  // --- k: silu * (1-exp(g)) (4-sparse), l2norm; dense decay row ---
  float4 kv4 = *(const float4*)(kk_ + base + l * 4);
  float kvv[4] = {kv4.x, kv4.y, kv4.z, kv4.w};
  float kmask[4], dd[4];
#pragma unroll
  for (int c = 0; c < 4; ++c) {
    int slot = l * 4 + c;
    float f = 0.f, d = 1.f;
#pragma unroll
    for (int it = 0; it < 4; ++it) {
      bool hit = (slot == widx[it]);
      f = hit ? wkfac[it] : f;
      d = hit ? wdec[it] : d;
    }
    kmask[c] = siluf(kvv[c]) * f;
    dd[c] = d;
  }
  float ss = kmask[0] * kmask[0] + kmask[1] * kmask[1] + kmask[2] * kmask[2] +
             kmask[3] * kmask[3];
  ss = wave_sum(ss);
  float kn = rsqrtf(ss + 1e-6f);
  *(float4*)(kk_ + base + l * 4) =
      make_float4(kmask[0] * kn, kmask[1] * kn, kmask[2] * kn, kmask[3] * kn);
  *(float4*)(decT + base + l * 4) = make_float4(dd[0], dd[1], dd[2], dd[3]);

  // --- q: silu, l2norm, * K^-0.5 ---
  float4 qv4 = *(const float4*)(qk + base + l * 4);
  float qs[4] = {siluf(qv4.x), siluf(qv4.y), siluf(qv4.z), siluf(qv4.w)};
  float qss =
      qs[0] * qs[0] + qs[1] * qs[1] + qs[2] * qs[2] + qs[3] * qs[3];
  qss = wave_sum(qss);
  float qn = rsqrtf(qss + 1e-6f) * 0.0625f;
  *(float4*)(qk + base + l * 4) =
      make_float4(qs[0] * qn, qs[1] * qn, qs[2] * qn, qs[3] * qn);

  // --- v: silu in place ---
  float4 vv4 = *(const float4*)(vv + base + l * 4);
  *(float4*)(vv + base + l * 4) =
      make_float4(siluf(vv4.x), siluf(vv4.y), siluf(vv4.z), siluf(vv4.w));
}

// ---------------- sequential gated delta-rule scan ----------------
// grid: 16 bh * 64 col-chunks; block 64. lane = kg(16 row-groups) x j(4 cols).
// Each lane holds 16 state rows (one column) in VGPRs.
__global__ __launch_bounds__(64) void scan_kernel(
    const float* __restrict__ q, const float* __restrict__ k,
    const float* __restrict__ dec, const float* __restrict__ v,
    const float* __restrict__ betaT, float* __restrict__ o) {
  const int blk = blockIdx.x;
  const int bh = blk >> 6;
  const int chunk = blk & 63;
  const int b = bh >> 2, h = bh & 3;
  const int lane = threadIdx.x;
  const int kg = lane >> 2;
  const int j = lane & 3;
  const int col = chunk * 4 + j;

  float S[16];
#pragma unroll
  for (int r = 0; r < 16; ++r) S[r] = 0.f;

  const size_t base0 = (size_t)(b * TT) * DD + h * 256;
  const float* qp = q + base0 + kg * 16;
  const float* kp = k + base0 + kg * 16;
  const float* dp = dec + base0 + kg * 16;
  const float* vp = v + base0 + col;
  const float* bp = betaT + (size_t)bh * TT;
  float* op = o + base0 + col;

  float4 qA[4], kA[4], dA[4], qB[4], kB[4], dB[4];
  float vA, vB, beA, beB;

#define LOADSTEP(t, qq, kk2, dd2, vvv, bbb)                       \
  {                                                               \
    const size_t off_ = (size_t)(t) * DD;                         \
    _Pragma("unroll") for (int i_ = 0; i_ < 4; ++i_) {            \
      qq[i_] = *(const float4*)(qp + off_ + i_ * 4);              \
      kk2[i_] = *(const float4*)(kp + off_ + i_ * 4);             \
      dd2[i_] = *(const float4*)(dp + off_ + i_ * 4);             \
    }                                                             \
    vvv = vp[off_];                                               \
    bbb = bp[t];                                                  \
  }

#define COMPSTEP(t, qq, kk2, dd2, vvv, bbb)                       \
  {                                                               \
    float ep = 0.f;                                               \
    _Pragma("unroll") for (int i_ = 0; i_ < 4; ++i_) {            \
      S[4 * i_ + 0] *= dd2[i_].x;                                 \
      ep = fmaf(kk2[i_].x, S[4 * i_ + 0], ep);                    \
      S[4 * i_ + 1] *= dd2[i_].y;                                 \
      ep = fmaf(kk2[i_].y, S[4 * i_ + 1], ep);                    \
      S[4 * i_ + 2] *= dd2[i_].z;                                 \
      ep = fmaf(kk2[i_].z, S[4 * i_ + 2], ep);                    \
      S[4 * i_ + 3] *= dd2[i_].w;                                 \
      ep = fmaf(kk2[i_].w, S[4 * i_ + 3], ep);                    \
    }                                                             \
    ep += __shfl_xor(ep, 4);                                      \
    ep += __shfl_xor(ep, 8);                                      \
    ep += __shfl_xor(ep, 16);                                     \
    ep += __shfl_xor(ep, 32);                                     \
    float err = vvv - ep;                                         \
    float be = bbb * err;                                         \
    float oacc = 0.f;                                             \
    _Pragma("unroll") for (int i_ = 0; i_ < 4; ++i_) {            \
      S[4 * i_ + 0] = fmaf(kk2[i_].x, be, S[4 * i_ + 0]);         \
      oacc = fmaf(qq[i_].x, S[4 * i_ + 0], oacc);                 \
      S[4 * i_ + 1] = fmaf(kk2[i_].y, be, S[4 * i_ + 1]);         \
      oacc = fmaf(qq[i_].y, S[4 * i_ + 1], oacc);                 \
      S[4 * i_ + 2] = fmaf(kk2[i_].z, be, S[4 * i_ + 2]);         \
      oacc = fmaf(qq[i_].z, S[4 * i_ + 2], oacc);                 \
      S[4 * i_ + 3] = fmaf(kk2[i_].w, be, S[4 * i_ + 3]);         \
      oacc = fmaf(qq[i_].w, S[4 * i_ + 3], oacc);                 \
    }                                                             \
    oacc += __shfl_xor(oacc, 4);                                  \
    oacc += __shfl_xor(oacc, 8);                                  \
    oacc += __shfl_xor(oacc, 16);                                 \
    oacc += __shfl_xor(oacc, 32);                                 \
    if (kg == 0) op[(size_t)(t) * DD] = oacc;                     \
  }

  LOADSTEP(0, qA, kA, dA, vA, beA);
  for (int t = 0; t < TT; t += 2) {
    LOADSTEP(t + 1, qB, kB, dB, vB, beB);
    COMPSTEP(t, qA, kA, dA, vA, beA);
    if (t + 2 < TT) LOADSTEP(t + 2, qA, kA, dA, vA, beA);
    COMPSTEP(t + 1, qB, kB, dB, vB, beB);
  }
#undef LOADSTEP
#undef COMPSTEP
}

// ---------------- per-head RMSNorm ----------------
__global__ __launch_bounds__(256) void rmsnorm_kernel(
    const float* __restrict__ o, const float* __restrict__ w,
    float* __restrict__ out) {
  const int row = blockIdx.x;
  const int h = threadIdx.x >> 6;
  const int l = threadIdx.x & 63;
  const size_t base = (size_t)row * DD + h * 256 + l * 4;
  float4 x = *(const float4*)(o + base);
  float ss = x.x * x.x + x.y * x.y + x.z * x.z + x.w * x.w;
  ss = wave_sum(ss);
  float sc = rsqrtf(ss * (1.f / 256.f) + 1e-5f);
  float4 wv = *(const float4*)(w + l * 4);
  *(float4*)(out + base) = make_float4(x.x * sc * wv.x, x.y * sc * wv.y,
                                       x.z * sc * wv.z, x.w * sc * wv.w);
}

extern "C" void kernel_launch(void* const* d_in, const int* in_sizes, int n_in,
                              void* d_out, int out_size, void* d_ws,
                              size_t ws_size, hipStream_t stream) {
  const float* hidden = (const float*)d_in[0];
  const float* Wq = (const float*)d_in[1];
  const float* Wk = (const float*)d_in[2];
  const float* Wv = (const float*)d_in[3];
  const float* Wa = (const float*)d_in[4];
  const float* Wr = (const float*)d_in[5];
  const float* Wb = (const float*)d_in[6];
  const float* dt = (const float*)d_in[7];
  const float* norm_w = (const float*)d_in[8];
  const float* Wo = (const float*)d_in[9];
  float* out = (float*)d_out;

  const size_t NP = (size_t)BB * TT * DD;  // 8192*1024
  float* ws = (float*)d_ws;
  float* qproj = ws;
  float* kproj = ws + NP;
  float* vproj = ws + 2 * NP;
  float* decT = ws + 3 * NP;
  float* obuf = ws + 4 * NP;
  float* betaT = ws + 5 * NP;  // 16*2048 floats
  float* rproj = out;          // use output buffer as scratch for r-projection
  float* normed = qproj;       // qproj dead after scan

  dim3 gg(1024 / 64, 8192 / 64), bt(256);
  sgemm_nn<<<gg, bt, 0, stream>>>(hidden, Wq, qproj, 8192, 1024, 1024);
  sgemm_nn<<<gg, bt, 0, stream>>>(hidden, Wk, kproj, 8192, 1024, 1024);
  sgemm_nn<<<gg, bt, 0, stream>>>(hidden, Wv, vproj, 8192, 1024, 1024);
  sgemm_nn<<<gg, bt, 0, stream>>>(hidden, Wr, rproj, 8192, 1024, 1024);
  routing_kernel<<<8192, 256, 0, stream>>>(hidden, Wa, Wb, dt, rproj, qproj,
                                           kproj, vproj, decT, betaT);
  scan_kernel<<<1024, 64, 0, stream>>>(qproj, kproj, decT, vproj, betaT, obuf);
  rmsnorm_kernel<<<8192, 256, 0, stream>>>(obuf, norm_w, normed);
  sgemm_nn<<<gg, bt, 0, stream>>>(normed, Wo, out, 8192, 1024, 1024);
}

// Round 2
// 2018.012 us; speedup vs baseline: 1.3641x; 1.3641x over previous
//
#include <hip/hip_runtime.h>
#include <hip/hip_bf16.h>

#define TT 2048
#define BB 4
#define HH 4
#define DD 1024

using bf16x8 = __attribute__((ext_vector_type(8))) short;
using f32x4  = __attribute__((ext_vector_type(4))) float;

__device__ __forceinline__ float wave_sum(float x) {
#pragma unroll
  for (int off = 32; off >= 1; off >>= 1) x += __shfl_xor(x, off);
  return x;
}

__device__ __forceinline__ float siluf(float x) {
  return x / (1.f + expf(-x));
}

__device__ __forceinline__ unsigned short f2bf(float f) {
  unsigned u = __float_as_uint(f);
  u = (u + 0x7fffu + ((u >> 16) & 1u)) >> 16;
  return (unsigned short)u;
}

// ---------------- fp32 tiled GEMM (kept for rproj: top-k needs fp32) ----
__global__ __launch_bounds__(256) void sgemm_nn(const float* __restrict__ A,
                                                const float* __restrict__ B,
                                                float* __restrict__ C, int M,
                                                int N, int K) {
  __shared__ float As[16][64];
  __shared__ float Bs[16][64];
  const int tid = threadIdx.x;
  const int brow = blockIdx.y * 64;
  const int bcol = blockIdx.x * 64;
  const int tm = (tid >> 4) << 2;
  const int tn = (tid & 15) << 2;
  const int la_r = tid >> 2;
  const int la_k = (tid & 3) << 2;
  const int lb_k = tid >> 4;
  const int lb_n = (tid & 15) << 2;
  float acc[4][4];
#pragma unroll
  for (int i = 0; i < 4; ++i)
#pragma unroll
    for (int jj = 0; jj < 4; ++jj) acc[i][jj] = 0.f;

  for (int k0 = 0; k0 < K; k0 += 16) {
    float4 av = *(const float4*)(A + (size_t)(brow + la_r) * K + k0 + la_k);
    float4 bv = *(const float4*)(B + (size_t)(k0 + lb_k) * N + bcol + lb_n);
    __syncthreads();
    As[la_k + 0][la_r] = av.x;
    As[la_k + 1][la_r] = av.y;
    As[la_k + 2][la_r] = av.z;
    As[la_k + 3][la_r] = av.w;
    *(float4*)(&Bs[lb_k][lb_n]) = bv;
    __syncthreads();
#pragma unroll
    for (int kk = 0; kk < 16; ++kk) {
      float4 a4 = *(const float4*)(&As[kk][tm]);
      float4 b4 = *(const float4*)(&Bs[kk][tn]);
      float a_[4] = {a4.x, a4.y, a4.z, a4.w};
      float b_[4] = {b4.x, b4.y, b4.z, b4.w};
#pragma unroll
      for (int i = 0; i < 4; ++i)
#pragma unroll
        for (int jj = 0; jj < 4; ++jj) acc[i][jj] = fmaf(a_[i], b_[jj], acc[i][jj]);
    }
  }
#pragma unroll
  for (int i = 0; i < 4; ++i) {
    float4 r = make_float4(acc[i][0], acc[i][1], acc[i][2], acc[i][3]);
    *(float4*)(C + (size_t)(brow + tm + i) * N + bcol + tn) = r;
  }
}

// ---------------- bf16 MFMA GEMM: C[M,N] = A[M,K] @ B[K,N], Bt is [N][K] ----
// 128x128 tile, BK=64, 256 threads (2x2 waves of 64x64), 16x16x32 bf16 MFMA.
// LDS XOR-swizzled (slot ^= row&7 on 16B slots) for conflict-free ds_read_b128.
__global__ __launch_bounds__(256) void gemm_bt(const unsigned short* __restrict__ A,
                                               const unsigned short* __restrict__ Bt,
                                               float* __restrict__ C,
                                               int M, int N, int K) {
  __shared__ unsigned short As[128 * 64];
  __shared__ unsigned short Bs[128 * 64];
  const int tid = threadIdx.x;
  const int l = tid & 63;
  const int w = tid >> 6;
  const int wm = w >> 1, wn = w & 1;
  const int m0 = blockIdx.y * 128, n0 = blockIdx.x * 128;

  f32x4 acc[4][4];
#pragma unroll
  for (int i = 0; i < 4; ++i)
#pragma unroll
    for (int j = 0; j < 4; ++j) acc[i][j] = (f32x4){0.f, 0.f, 0.f, 0.f};

  // staging geometry: chunk = it*256+tid in [0,1024): row=chunk>>3, s=chunk&7
  int c_row[4], c_slot[4], c_dst[4];
#pragma unroll
  for (int it = 0; it < 4; ++it) {
    int chunk = it * 256 + tid;
    int row = chunk >> 3, s = chunk & 7;
    c_row[it] = row;
    c_slot[it] = s;
    c_dst[it] = row * 128 + ((s ^ (row & 7)) << 4);  // swizzled byte offset
  }
  // fragment read byte offsets (lane l reads row base+(l&15), k-chunk (l>>4))
  int ra_off[2][4], rb_off[2][4];
#pragma unroll
  for (int kh = 0; kh < 2; ++kh)
#pragma unroll
    for (int f = 0; f < 4; ++f) {
      int rowA = wm * 64 + f * 16 + (l & 15);
      ra_off[kh][f] = rowA * 128 + (((kh * 4 + (l >> 4)) ^ (rowA & 7)) << 4);
      int rowB = wn * 64 + f * 16 + (l & 15);
      rb_off[kh][f] = rowB * 128 + (((kh * 4 + (l >> 4)) ^ (rowB & 7)) << 4);
    }

  for (int k0 = 0; k0 < K; k0 += 64) {
    uint4 ra[4], rb[4];
#pragma unroll
    for (int it = 0; it < 4; ++it) {
      ra[it] = *(const uint4*)(A + (size_t)(m0 + c_row[it]) * K + k0 + c_slot[it] * 8);
      rb[it] = *(const uint4*)(Bt + (size_t)(n0 + c_row[it]) * K + k0 + c_slot[it] * 8);
    }
    __syncthreads();
#pragma unroll
    for (int it = 0; it < 4; ++it) {
      *(uint4*)((char*)As + c_dst[it]) = ra[it];
      *(uint4*)((char*)Bs + c_dst[it]) = rb[it];
    }
    __syncthreads();
#pragma unroll
    for (int kh = 0; kh < 2; ++kh) {
      bf16x8 af[4], bfv[4];
#pragma unroll
      for (int f = 0; f < 4; ++f) {
        af[f] = *(const bf16x8*)((const char*)As + ra_off[kh][f]);
        bfv[f] = *(const bf16x8*)((const char*)Bs + rb_off[kh][f]);
      }
#pragma unroll
      for (int i = 0; i < 4; ++i)
#pragma unroll
        for (int j = 0; j < 4; ++j)
          acc[i][j] = __builtin_amdgcn_mfma_f32_16x16x32_bf16(af[i], bfv[j],
                                                              acc[i][j], 0, 0, 0);
    }
  }
  // C/D layout (m89-verified): col = lane&15, row = (lane>>4)*4 + reg
  const int cn = n0 + wn * 64 + (l & 15);
  const int rbase = m0 + wm * 64 + ((l >> 4) << 2);
#pragma unroll
  for (int i = 0; i < 4; ++i)
#pragma unroll
    for (int j = 0; j < 4; ++j)
#pragma unroll
      for (int r = 0; r < 4; ++r)
        C[(size_t)(rbase + i * 16 + r) * N + cn + j * 16] = acc[i][j][r];
}

// ---------------- casts ----------------
__global__ __launch_bounds__(256) void cast_bf16_kernel(const float* __restrict__ in,
                                                        unsigned short* __restrict__ out) {
  const size_t i = ((size_t)blockIdx.x * 256 + threadIdx.x) * 4;
  float4 x = *(const float4*)(in + i);
  ushort4 o4;
  o4.x = f2bf(x.x);
  o4.y = f2bf(x.y);
  o4.z = f2bf(x.z);
  o4.w = f2bf(x.w);
  *(ushort4*)(out + i) = o4;
}

// W [R][C] f32 row-major -> WT [C][R] bf16 (transpose + cast)
__global__ __launch_bounds__(256) void tcast_kernel(const float* __restrict__ W,
                                                    unsigned short* __restrict__ WT,
                                                    int R, int C) {
  __shared__ float tile[32][33];
  const int tx = threadIdx.x, ty = threadIdx.y;
  const int c0 = blockIdx.x * 32, r0 = blockIdx.y * 32;
#pragma unroll
  for (int i = 0; i < 4; ++i)
    tile[ty + 8 * i][tx] = W[(size_t)(r0 + ty + 8 * i) * C + c0 + tx];
  __syncthreads();
#pragma unroll
  for (int i = 0; i < 4; ++i)
    WT[(size_t)(c0 + ty + 8 * i) * R + r0 + tx] = f2bf(tile[tx][ty + 8 * i]);
}

// ---------------- routing: a/beta dots, top-4, silu+norms, dense decay ----
__global__ __launch_bounds__(256) void routing_kernel(
    const float* __restrict__ hidden, const float* __restrict__ Wa,
    const float* __restrict__ Wb, const float* __restrict__ dt,
    const float* __restrict__ rproj, float* __restrict__ qk,
    float* __restrict__ kk_, float* __restrict__ vv, float* __restrict__ decT,
    float* __restrict__ betaT) {
  const int row = blockIdx.x;  // b*T + t
  const int b = row >> 11;
  const int t = row & (TT - 1);
  const int h = threadIdx.x >> 6;
  const int l = threadIdx.x & 63;
  const size_t base = (size_t)row * DD + h * 256;

  const float* hrow = hidden + (size_t)row * DD;
  float aa = 0.f, bb = 0.f;
#pragma unroll
  for (int i = 0; i < 16; ++i) {
    float hv = hrow[l + 64 * i];
    aa = fmaf(hv, Wa[(l + 64 * i) * HH + h], aa);
    bb = fmaf(hv, Wb[(l + 64 * i) * HH + h], bb);
  }
  aa = wave_sum(aa);
  bb = wave_sum(bb);
  float sp = (aa > 20.f) ? aa : log1pf(expf(aa));
  float a_ = -sp * expf(dt[h]);
  float beta = 1.f / (1.f + expf(-bb));
  const int bh = b * HH + h;
  if (l == 0) betaT[(size_t)bh * TT + t] = beta;

  float4 rt4 = *(const float4*)(rproj + base + l * 4);
  float rv[4] = {rt4.x, rt4.y, rt4.z, rt4.w};
  int used = 0;
  int widx[4];
  float wsig[4], wdec[4], wkfac[4];
#pragma unroll
  for (int it = 0; it < 4; ++it) {
    float bv = -3.4e38f;
    int bi = 0x7fffffff;
#pragma unroll
    for (int c = 0; c < 4; ++c) {
      bool ok = !(used & (1 << c));
      float v = rv[c];
      if (ok && (v > bv)) {
        bv = v;
        bi = l * 4 + c;
      }
    }
#pragma unroll
    for (int off = 32; off >= 1; off >>= 1) {
      float ov = __shfl_xor(bv, off);
      int oi = __shfl_xor(bi, off);
      if (ov > bv || (ov == bv && oi < bi)) {
        bv = ov;
        bi = oi;
      }
    }
    widx[it] = bi;
    wsig[it] = 1.f / (1.f + expf(-bv));
    if ((bi >> 2) == l) used |= 1 << (bi & 3);
  }
  float wsum = wsig[0] + wsig[1] + wsig[2] + wsig[3] + 1e-6f;
#pragma unroll
  for (int it = 0; it < 4; ++it) {
    float g = a_ * (wsig[it] / wsum);
    wdec[it] = expf(g);
    wkfac[it] = 1.f - wdec[it];
  }

  float4 kv4 = *(const float4*)(kk_ + base + l * 4);
  float kvv[4] = {kv4.x, kv4.y, kv4.z, kv4.w};
  float kmask[4], ddv[4];
#pragma unroll
  for (int c = 0; c < 4; ++c) {
    int slot = l * 4 + c;
    float f = 0.f, d = 1.f;
#pragma unroll
    for (int it = 0; it < 4; ++it) {
      bool hit = (slot == widx[it]);
      f = hit ? wkfac[it] : f;
      d = hit ? wdec[it] : d;
    }
    kmask[c] = siluf(kvv[c]) * f;
    ddv[c] = d;
  }
  float ss = kmask[0] * kmask[0] + kmask[1] * kmask[1] + kmask[2] * kmask[2] +
             kmask[3] * kmask[3];
  ss = wave_sum(ss);
  float kn = rsqrtf(ss + 1e-6f);
  *(float4*)(kk_ + base + l * 4) =
      make_float4(kmask[0] * kn, kmask[1] * kn, kmask[2] * kn, kmask[3] * kn);
  *(float4*)(decT + base + l * 4) = make_float4(ddv[0], ddv[1], ddv[2], ddv[3]);

  float4 qv4 = *(const float4*)(qk + base + l * 4);
  float qs[4] = {siluf(qv4.x), siluf(qv4.y), siluf(qv4.z), siluf(qv4.w)};
  float qss = qs[0] * qs[0] + qs[1] * qs[1] + qs[2] * qs[2] + qs[3] * qs[3];
  qss = wave_sum(qss);
  float qn = rsqrtf(qss + 1e-6f) * 0.0625f;
  *(float4*)(qk + base + l * 4) =
      make_float4(qs[0] * qn, qs[1] * qn, qs[2] * qn, qs[3] * qn);

  float4 vv4 = *(const float4*)(vv + base + l * 4);
  *(float4*)(vv + base + l * 4) =
      make_float4(siluf(vv4.x), siluf(vv4.y), siluf(vv4.z), siluf(vv4.w));
}

// ---------------- sequential gated delta-rule scan ----------------
// 2048 blocks x 64 threads. block = (bh, colpair). lane = (kg in [0,32), j in [0,2)).
// Each lane: 8 state rows (kg*8..+7) of one column. Prefetch distance 3.
__global__ __launch_bounds__(64, 4) void scan_kernel(
    const float* __restrict__ q, const float* __restrict__ k,
    const float* __restrict__ dec, const float* __restrict__ v,
    const float* __restrict__ betaT, float* __restrict__ o) {
  const int blk = blockIdx.x;
  const int bh = blk >> 7;
  const int cp = blk & 127;
  const int b = bh >> 2, h = bh & 3;
  const int lane = threadIdx.x;
  const int kg = lane >> 1;
  const int j = lane & 1;
  const int col = cp * 2 + j;

  float S[8];
#pragma unroll
  for (int r = 0; r < 8; ++r) S[r] = 0.f;

  const size_t base0 = (size_t)(b * TT) * DD + h * 256;
  const float* qp = q + base0 + kg * 8;
  const float* kp = k + base0 + kg * 8;
  const float* dp = dec + base0 + kg * 8;
  const float* vp = v + base0 + col;
  const float* bp = betaT + (size_t)bh * TT;
  float* op = o + base0 + col;

  float4 qA[2], kA[2], dA[2], qB[2], kB[2], dB[2];
  float4 qC[2], kC[2], dC[2], qD[2], kD[2], dD[2];
  float vA, vB, vC, vD, bA, bB, bC, bD;

#define LOADS(Q, Kb, Db, Vv, Bb, t)                                \
  {                                                                \
    int tc = (t) < TT ? (t) : (TT - 1);                            \
    size_t off_ = (size_t)tc * DD;                                 \
    Q[0] = *(const float4*)(qp + off_);                            \
    Q[1] = *(const float4*)(qp + off_ + 4);                        \
    Kb[0] = *(const float4*)(kp + off_);                           \
    Kb[1] = *(const float4*)(kp + off_ + 4);                       \
    Db[0] = *(const float4*)(dp + off_);                           \
    Db[1] = *(const float4*)(dp + off_ + 4);                       \
    Vv = vp[off_];                                                 \
    Bb = bp[tc];                                                   \
  }

#define COMPS(Q, Kb, Db, Vv, Bb, t)                                \
  {                                                                \
    S[0] *= Db[0].x; S[1] *= Db[0].y; S[2] *= Db[0].z; S[3] *= Db[0].w; \
    S[4] *= Db[1].x; S[5] *= Db[1].y; S[6] *= Db[1].z; S[7] *= Db[1].w; \
    float e0 = S[0] * Kb[0].x;                                     \
    float e1 = S[4] * Kb[1].x;                                     \
    e0 = fmaf(Kb[0].y, S[1], e0);                                  \
    e1 = fmaf(Kb[1].y, S[5], e1);                                  \
    e0 = fmaf(Kb[0].z, S[2], e0);                                  \
    e1 = fmaf(Kb[1].z, S[6], e1);                                  \
    e0 = fmaf(Kb[0].w, S[3], e0);                                  \
    e1 = fmaf(Kb[1].w, S[7], e1);                                  \
    float ep = e0 + e1;                                            \
    ep += __shfl_xor(ep, 2);                                       \
    ep += __shfl_xor(ep, 4);                                       \
    ep += __shfl_xor(ep, 8);                                       \
    ep += __shfl_xor(ep, 16);                                      \
    ep += __shfl_xor(ep, 32);                                      \
    float be = Bb * (Vv - ep);                                     \
    S[0] = fmaf(Kb[0].x, be, S[0]);                                \
    S[1] = fmaf(Kb[0].y, be, S[1]);                                \
    S[2] = fmaf(Kb[0].z, be, S[2]);                                \
    S[3] = fmaf(Kb[0].w, be, S[3]);                                \
    S[4] = fmaf(Kb[1].x, be, S[4]);                                \
    S[5] = fmaf(Kb[1].y, be, S[5]);                                \
    S[6] = fmaf(Kb[1].z, be, S[6]);                                \
    S[7] = fmaf(Kb[1].w, be, S[7]);                                \
    float o0 = S[0] * Q[0].x;                                      \
    float o1 = S[4] * Q[1].x;                                      \
    o0 = fmaf(Q[0].y, S[1], o0);                                   \
    o1 = fmaf(Q[1].y, S[5], o1);                                   \
    o0 = fmaf(Q[0].z, S[2], o0);                                   \
    o1 = fmaf(Q[1].z, S[6], o1);                                   \
    o0 = fmaf(Q[0].w, S[3], o0);                                   \
    o1 = fmaf(Q[1].w, S[7], o1);                                   \
    float oa = o0 + o1;                                            \
    oa += __shfl_xor(oa, 2);                                       \
    oa += __shfl_xor(oa, 4);                                       \
    oa += __shfl_xor(oa, 8);                                       \
    oa += __shfl_xor(oa, 16);                                      \
    oa += __shfl_xor(oa, 32);                                      \
    if (kg == 0) op[(size_t)(t) * DD] = oa;                        \
  }

  LOADS(qA, kA, dA, vA, bA, 0);
  LOADS(qB, kB, dB, vB, bB, 1);
  LOADS(qC, kC, dC, vC, bC, 2);
  for (int t = 0; t < TT; t += 4) {
    LOADS(qD, kD, dD, vD, bD, t + 3);
    COMPS(qA, kA, dA, vA, bA, t);
    LOADS(qA, kA, dA, vA, bA, t + 4);
    COMPS(qB, kB, dB, vB, bB, t + 1);
    LOADS(qB, kB, dB, vB, bB, t + 5);
    COMPS(qC, kC, dC, vC, bC, t + 2);
    LOADS(qC, kC, dC, vC, bC, t + 6);
    COMPS(qD, kD, dD, vD, bD, t + 3);
  }
#undef LOADS
#undef COMPS
}

// ---------------- per-head RMSNorm ----------------
__global__ __launch_bounds__(256) void rmsnorm_kernel(
    const float* __restrict__ o, const float* __restrict__ w,
    float* __restrict__ out) {
  const int row = blockIdx.x;
  const int l = threadIdx.x & 63;
  const size_t base = (size_t)row * DD + (threadIdx.x >> 6) * 256 + l * 4;
  float4 x = *(const float4*)(o + base);
  float ss = x.x * x.x + x.y * x.y + x.z * x.z + x.w * x.w;
  ss = wave_sum(ss);
  float sc = rsqrtf(ss * (1.f / 256.f) + 1e-5f);
  float4 wv = *(const float4*)(w + l * 4);
  *(float4*)(out + base) = make_float4(x.x * sc * wv.x, x.y * sc * wv.y,
                                       x.z * sc * wv.z, x.w * sc * wv.w);
}

extern "C" void kernel_launch(void* const* d_in, const int* in_sizes, int n_in,
                              void* d_out, int out_size, void* d_ws,
                              size_t ws_size, hipStream_t stream) {
  const float* hidden = (const float*)d_in[0];
  const float* Wq = (const float*)d_in[1];
  const float* Wk = (const float*)d_in[2];
  const float* Wv = (const float*)d_in[3];
  const float* Wa = (const float*)d_in[4];
  const float* Wr = (const float*)d_in[5];
  const float* Wb = (const float*)d_in[6];
  const float* dt = (const float*)d_in[7];
  const float* norm_w = (const float*)d_in[8];
  const float* Wo = (const float*)d_in[9];
  float* out = (float*)d_out;

  const size_t NP = (size_t)BB * TT * DD;  // 8388608
  float* ws = (float*)d_ws;
  float* qproj = ws;
  float* kproj = ws + NP;
  float* vproj = ws + 2 * NP;
  float* decT = ws + 3 * NP;
  unsigned short* hbf = (unsigned short*)(ws + 4 * NP);        // NP bf16
  unsigned short* wT = (unsigned short*)(ws + 4 * NP + NP / 2);  // 4 x 1M bf16
  float* betaT = ws + 4 * NP + NP / 2 + 2 * 1024 * 1024;       // 16*2048 floats
  unsigned short* WT0 = wT;                // Wq^T
  unsigned short* WT1 = wT + 1048576;      // Wk^T
  unsigned short* WT2 = wT + 2 * 1048576;  // Wv^T
  unsigned short* WT3 = wT + 3 * 1048576;  // Wo^T
  float* rproj = out;   // scratch: output buffer holds r-projection
  float* normed = qproj;

  // rproj in fp32 (top-k routing is discontinuous; keep exact-ish)
  dim3 gg32(1024 / 64, 8192 / 64), bt(256);
  sgemm_nn<<<gg32, bt, 0, stream>>>(hidden, Wr, rproj, 8192, 1024, 1024);

  // casts
  cast_bf16_kernel<<<8192, 256, 0, stream>>>(hidden, hbf);
  dim3 tg(32, 32), tb(32, 8);
  tcast_kernel<<<tg, tb, 0, stream>>>(Wq, WT0, 1024, 1024);
  tcast_kernel<<<tg, tb, 0, stream>>>(Wk, WT1, 1024, 1024);
  tcast_kernel<<<tg, tb, 0, stream>>>(Wv, WT2, 1024, 1024);
  tcast_kernel<<<tg, tb, 0, stream>>>(Wo, WT3, 1024, 1024);

  // bf16 MFMA projections
  dim3 gmm(1024 / 128, 8192 / 128);
  gemm_bt<<<gmm, bt, 0, stream>>>(hbf, WT0, qproj, 8192, 1024, 1024);
  gemm_bt<<<gmm, bt, 0, stream>>>(hbf, WT1, kproj, 8192, 1024, 1024);
  gemm_bt<<<gmm, bt, 0, stream>>>(hbf, WT2, vproj, 8192, 1024, 1024);

  routing_kernel<<<8192, 256, 0, stream>>>(hidden, Wa, Wb, dt, rproj, qproj,
                                           kproj, vproj, decT, betaT);
  scan_kernel<<<2048, 64, 0, stream>>>(qproj, kproj, decT, vproj, betaT, out);
  rmsnorm_kernel<<<8192, 256, 0, stream>>>(out, norm_w, normed);
  cast_bf16_kernel<<<8192, 256, 0, stream>>>(normed, hbf);
  gemm_bt<<<gmm, bt, 0, stream>>>(hbf, WT3, out, 8192, 1024, 1024);
}